// Round 2
// baseline (342.000 us; speedup 1.0000x reference)
//
#include <hip/hip_runtime.h>
#include <math.h>

#define NC 32
#define NH 1024
#define NW 1024
#define NGH 8
#define NGW 8
#define NTH 128
#define NTW 128
#define NBINS 256
#define NTILES (NC*NGH*NGW)          /* 2048 */
#define NPIXTOT (NC*NH*NW)           /* 33554432 */
#define TPIX (NTH*NTW)               /* 16384 */

/* workspace layout (bytes) */
#define OFF_PSUM   0                          /* double[2048] */
#define OFF_PSQ    16384                      /* double[2048] */
#define OFF_PMIN   32768                      /* float[2048]  */
#define OFF_PMAX   40960                      /* float[2048]  */
#define OFF_PARAMS 49152                      /* float[16]    */
#define OFF_HIST   65536                      /* uint[NTILES*NBINS] = 2MB */
#define OFF_LUT    (OFF_HIST + NTILES*NBINS*4)/* float[NTILES*NBINS] = 2MB */

/* ---------------- kernel 1: fused sum/sumsq/min/max partial reduce ------- */
__global__ __launch_bounds__(256) void k_reduce(const float* __restrict__ x,
                                                double* __restrict__ ps,
                                                double* __restrict__ ps2,
                                                float* __restrict__ pmn,
                                                float* __restrict__ pmx) {
    int tid = threadIdx.x;
    long g = (long)blockIdx.x * 256 + tid;
    double s = 0.0, s2 = 0.0;
    float mn = INFINITY, mx = -INFINITY;
    const float4* x4 = (const float4*)x;
    const long n4 = NPIXTOT / 4;
    for (long i = g; i < n4; i += (long)2048 * 256) {
        float4 v = x4[i];
        s  += (double)v.x + (double)v.y + (double)v.z + (double)v.w;
        s2 += (double)v.x * v.x + (double)v.y * v.y + (double)v.z * v.z + (double)v.w * v.w;
        mn = fminf(mn, fminf(fminf(v.x, v.y), fminf(v.z, v.w)));
        mx = fmaxf(mx, fmaxf(fmaxf(v.x, v.y), fmaxf(v.z, v.w)));
    }
    for (int o = 32; o; o >>= 1) {
        s  += __shfl_down(s, o);
        s2 += __shfl_down(s2, o);
        mn = fminf(mn, __shfl_down(mn, o));
        mx = fmaxf(mx, __shfl_down(mx, o));
    }
    __shared__ double shs[4], shs2[4];
    __shared__ float shmn[4], shmx[4];
    int wid = tid >> 6, lane = tid & 63;
    if (lane == 0) { shs[wid] = s; shs2[wid] = s2; shmn[wid] = mn; shmx[wid] = mx; }
    __syncthreads();
    if (tid == 0) {
        double S  = shs[0] + shs[1] + shs[2] + shs[3];
        double S2 = shs2[0] + shs2[1] + shs2[2] + shs2[3];
        float MN = fminf(fminf(shmn[0], shmn[1]), fminf(shmn[2], shmn[3]));
        float MX = fmaxf(fmaxf(shmx[0], shmx[1]), fmaxf(shmx[2], shmx[3]));
        ps[blockIdx.x] = S; ps2[blockIdx.x] = S2; pmn[blockIdx.x] = MN; pmx[blockIdx.x] = MX;
    }
}

/* ---------------- kernel 2: final reduce + scalar params ----------------- */
__global__ __launch_bounds__(256) void k_params(const double* __restrict__ ps,
                                                const double* __restrict__ ps2,
                                                const float* __restrict__ pmn,
                                                const float* __restrict__ pmx,
                                                float* __restrict__ params) {
    int tid = threadIdx.x;
    double s = 0.0, s2 = 0.0;
    float mn = INFINITY, mx = -INFINITY;
    for (int i = tid; i < 2048; i += 256) {
        s += ps[i]; s2 += ps2[i];
        mn = fminf(mn, pmn[i]); mx = fmaxf(mx, pmx[i]);
    }
    for (int o = 32; o; o >>= 1) {
        s  += __shfl_down(s, o);
        s2 += __shfl_down(s2, o);
        mn = fminf(mn, __shfl_down(mn, o));
        mx = fmaxf(mx, __shfl_down(mx, o));
    }
    __shared__ double shs[4], shs2[4];
    __shared__ float shmn[4], shmx[4];
    int wid = tid >> 6, lane = tid & 63;
    if (lane == 0) { shs[wid] = s; shs2[wid] = s2; shmn[wid] = mn; shmx[wid] = mx; }
    __syncthreads();
    if (tid == 0) {
        double S  = shs[0] + shs[1] + shs[2] + shs[3];
        double S2 = shs2[0] + shs2[1] + shs2[2] + shs2[3];
        float MN = fminf(fminf(shmn[0], shmn[1]), fminf(shmn[2], shmn[3]));
        float MX = fmaxf(fmaxf(shmx[0], shmx[1]), fmaxf(shmx[2], shmx[3]));
        const double n = (double)NPIXTOT;
        double var = (S2 - S * S / n) / (n - 1.0);
        double sd = sqrt(var > 0.0 ? var : 0.0);
        double range = (double)MX - (double)MN;
        double ct = sd / range;             /* std of doubly-normalized x */
        int flag = (ct < 0.05) ? 1 : 0;
        double beta = 10.0 * ct;
        double cl = 1.0 / (1.0 - beta) + beta;
        double mv = floor(cl * (double)TPIX / (double)NBINS);
        if (mv < 1.0) mv = 1.0;
        params[0] = MN;
        params[1] = (float)(1.0 / range);
        params[2] = (float)mv;
        ((int*)params)[3] = flag;
    }
}

/* ---------------- kernel 3: per-tile histogram (one block per tile) ------ */
__global__ __launch_bounds__(256) void k_hist(const float* __restrict__ x,
                                              const float* __restrict__ params,
                                              unsigned* __restrict__ hist) {
    __shared__ unsigned lh[NBINS];
    int tid = threadIdx.x;
    int t = blockIdx.x;
    lh[tid] = 0;
    __syncthreads();
    float xmin = params[0], inv = params[1];
    int c = t >> 6, gy = (t >> 3) & 7, gx = t & 7;
    const float* base = x + ((long)c * NH + (long)gy * NTH) * NW + gx * NTW;
    #pragma unroll
    for (int j = 0; j < 16; j++) {
        int l = j * 256 + tid;            /* float4 id within tile: 4096 total */
        int th = l >> 5, tw4 = l & 31;
        float4 v = *(const float4*)(base + (long)th * NW + tw4 * 4);
        float zv[4] = {v.x, v.y, v.z, v.w};
        #pragma unroll
        for (int k = 0; k < 4; k++) {
            float z = (zv[k] - xmin) * inv;
            int b = (int)(z * 256.0f);
            b = b < 0 ? 0 : (b > 255 ? 255 : b);
            atomicAdd(&lh[b], 1u);
        }
    }
    __syncthreads();
    hist[t * NBINS + tid] = lh[tid];
}

/* ---------------- kernel 4: clip+redistribute+cdf -> LUT ----------------- */
__global__ __launch_bounds__(256) void k_lut(const unsigned* __restrict__ hist,
                                             const float* __restrict__ params,
                                             float* __restrict__ lut) {
    int tid = threadIdx.x;
    int t = blockIdx.x;
    int mv = (int)params[2];
    int h = (int)hist[t * NBINS + tid];
    int cl = h < mv ? h : mv;
    __shared__ int sh[NBINS];
    sh[tid] = cl;
    __syncthreads();
    /* Hillis-Steele inclusive scan of clipped counts */
    for (int o = 1; o < NBINS; o <<= 1) {
        int v = (tid >= o) ? sh[tid - o] : 0;
        __syncthreads();
        sh[tid] += v;
        __syncthreads();
    }
    int total = sh[NBINS - 1];
    int cdfc = sh[tid];
    int excess = TPIX - total;
    int residual = excess & (NBINS - 1);
    int redist = excess >> 8;
    /* cdf of (clipped + redist + (bin<residual)) */
    int cdf = cdfc + redist * (tid + 1) + ((tid + 1) < residual ? (tid + 1) : residual);
    float lv = floorf(fminf((float)cdf * 255.0f / 16384.0f, 255.0f));
    lut[t * NBINS + tid] = lv < 0.0f ? 0.0f : lv;
}

/* ---------------- kernel 5: bilinear LUT interp + log2(1+x) -------------- */
__global__ __launch_bounds__(256) void k_out(const float* __restrict__ x,
                                             const float* __restrict__ params,
                                             const float* __restrict__ lut,
                                             float* __restrict__ out) {
    int tid = threadIdx.x;
    long fid = (long)blockIdx.x * 256 + tid;   /* float4 index */
    long p = fid * 4;
    int w = (int)(p & (NW - 1));
    int h = (int)((p >> 10) & (NH - 1));
    int c = (int)(p >> 20);
    float xmin = params[0], inv = params[1];
    int flag = ((const int*)params)[3];
    float4 v = *(const float4*)(x + p);
    float gy = (h + 0.5f) * (1.0f / NTH) - 0.5f;
    float fy = floorf(gy);
    float wy = gy - fy;
    int y0 = (int)fy; y0 = y0 < 0 ? 0 : (y0 > 7 ? 7 : y0);
    int y1 = y0 + 1 > 7 ? 7 : y0 + 1;
    const float* lutc = lut + (long)c * 64 * NBINS;
    float zv[4] = {v.x, v.y, v.z, v.w};
    float o4[4];
    #pragma unroll
    for (int k = 0; k < 4; k++) {
        float z = (zv[k] - xmin) * inv;
        float val;
        if (flag) {
            int wk = w + k;
            float gx = (wk + 0.5f) * (1.0f / NTW) - 0.5f;
            float fx = floorf(gx);
            float wx = gx - fx;
            int x0 = (int)fx; x0 = x0 < 0 ? 0 : (x0 > 7 ? 7 : x0);
            int x1 = x0 + 1 > 7 ? 7 : x0 + 1;
            int b = (int)(z * 255.0f);
            b = b < 0 ? 0 : (b > 255 ? 255 : b);
            const float* l00 = lutc + (y0 * 8 + x0) * NBINS;
            const float* l01 = lutc + (y0 * 8 + x1) * NBINS;
            const float* l10 = lutc + (y1 * 8 + x0) * NBINS;
            const float* l11 = lutc + (y1 * 8 + x1) * NBINS;
            float top = l00[b] * (1.0f - wx) + l01[b] * wx;
            float bot = l10[b] * (1.0f - wx) + l11[b] * wx;
            val = (top * (1.0f - wy) + bot * wy) * (1.0f / 255.0f);
        } else {
            val = z;
        }
        o4[k] = log2f(1.0f + val);
    }
    *(float4*)(out + p) = make_float4(o4[0], o4[1], o4[2], o4[3]);
}

extern "C" void kernel_launch(void* const* d_in, const int* in_sizes, int n_in,
                              void* d_out, int out_size, void* d_ws, size_t ws_size,
                              hipStream_t stream) {
    const float* x = (const float*)d_in[0];
    float* out = (float*)d_out;
    char* ws = (char*)d_ws;
    double* ps   = (double*)(ws + OFF_PSUM);
    double* ps2  = (double*)(ws + OFF_PSQ);
    float* pmn   = (float*)(ws + OFF_PMIN);
    float* pmx   = (float*)(ws + OFF_PMAX);
    float* params= (float*)(ws + OFF_PARAMS);
    unsigned* hist = (unsigned*)(ws + OFF_HIST);
    float* lut   = (float*)(ws + OFF_LUT);

    k_reduce<<<2048, 256, 0, stream>>>(x, ps, ps2, pmn, pmx);
    k_params<<<1, 256, 0, stream>>>(ps, ps2, pmn, pmx, params);
    k_hist<<<NTILES, 256, 0, stream>>>(x, params, hist);
    k_lut<<<NTILES, 256, 0, stream>>>(hist, params, lut);
    k_out<<<NPIXTOT / 1024, 256, 0, stream>>>(x, params, lut, out);
}

// Round 3
// 325.170 us; speedup vs baseline: 1.0518x; 1.0518x over previous
//
#include <hip/hip_runtime.h>
#include <math.h>

#define NC 32
#define NH 1024
#define NW 1024
#define NGH 8
#define NGW 8
#define NTH 128
#define NTW 128
#define NBINS 256
#define NTILES (NC*NGH*NGW)          /* 2048 */
#define NPIXTOT (NC*NH*NW)           /* 33554432 */
#define TPIX (NTH*NTW)               /* 16384 */

/* workspace layout (bytes) */
#define OFF_PSUM   0                          /* double[2048] */
#define OFF_PSQ    16384                      /* double[2048] */
#define OFF_PMIN   32768                      /* float[2048]  */
#define OFF_PMAX   40960                      /* float[2048]  */
#define OFF_PARAMS 49152                      /* float[16]    */
#define OFF_HIST   65536                      /* uint[NTILES*NBINS] = 2MB */
#define OFF_LUT    (OFF_HIST + NTILES*NBINS*4)/* float[NTILES*NBINS] = 2MB */

/* ---------------- kernel 1: fused sum/sumsq/min/max partial reduce ------- */
/* f32 pairwise within each float4, promote to f64 once per iteration:      */
/* cuts the f64 dependent-op count 4x (was 8 f64 ops/iter chained).          */
__global__ __launch_bounds__(256) void k_reduce(const float* __restrict__ x,
                                                double* __restrict__ ps,
                                                double* __restrict__ ps2,
                                                float* __restrict__ pmn,
                                                float* __restrict__ pmx) {
    int tid = threadIdx.x;
    long g = (long)blockIdx.x * 256 + tid;
    double s = 0.0, s2 = 0.0;
    float mn = INFINITY, mx = -INFINITY;
    const float4* x4 = (const float4*)x;
    const long n4 = NPIXTOT / 4;
    for (long i = g; i < n4; i += (long)2048 * 256) {
        float4 v = x4[i];
        float sf  = (v.x + v.y) + (v.z + v.w);
        float s2f = fmaf(v.x, v.x, fmaf(v.y, v.y, fmaf(v.z, v.z, v.w * v.w)));
        s  += (double)sf;
        s2 += (double)s2f;
        mn = fminf(mn, fminf(fminf(v.x, v.y), fminf(v.z, v.w)));
        mx = fmaxf(mx, fmaxf(fmaxf(v.x, v.y), fmaxf(v.z, v.w)));
    }
    for (int o = 32; o; o >>= 1) {
        s  += __shfl_down(s, o);
        s2 += __shfl_down(s2, o);
        mn = fminf(mn, __shfl_down(mn, o));
        mx = fmaxf(mx, __shfl_down(mx, o));
    }
    __shared__ double shs[4], shs2[4];
    __shared__ float shmn[4], shmx[4];
    int wid = tid >> 6, lane = tid & 63;
    if (lane == 0) { shs[wid] = s; shs2[wid] = s2; shmn[wid] = mn; shmx[wid] = mx; }
    __syncthreads();
    if (tid == 0) {
        double S  = shs[0] + shs[1] + shs[2] + shs[3];
        double S2 = shs2[0] + shs2[1] + shs2[2] + shs2[3];
        float MN = fminf(fminf(shmn[0], shmn[1]), fminf(shmn[2], shmn[3]));
        float MX = fmaxf(fmaxf(shmx[0], shmx[1]), fmaxf(shmx[2], shmx[3]));
        ps[blockIdx.x] = S; ps2[blockIdx.x] = S2; pmn[blockIdx.x] = MN; pmx[blockIdx.x] = MX;
    }
}

/* ---------------- kernel 2: final reduce + scalar params ----------------- */
__global__ __launch_bounds__(256) void k_params(const double* __restrict__ ps,
                                                const double* __restrict__ ps2,
                                                const float* __restrict__ pmn,
                                                const float* __restrict__ pmx,
                                                float* __restrict__ params) {
    int tid = threadIdx.x;
    double s = 0.0, s2 = 0.0;
    float mn = INFINITY, mx = -INFINITY;
    for (int i = tid; i < 2048; i += 256) {
        s += ps[i]; s2 += ps2[i];
        mn = fminf(mn, pmn[i]); mx = fmaxf(mx, pmx[i]);
    }
    for (int o = 32; o; o >>= 1) {
        s  += __shfl_down(s, o);
        s2 += __shfl_down(s2, o);
        mn = fminf(mn, __shfl_down(mn, o));
        mx = fmaxf(mx, __shfl_down(mx, o));
    }
    __shared__ double shs[4], shs2[4];
    __shared__ float shmn[4], shmx[4];
    int wid = tid >> 6, lane = tid & 63;
    if (lane == 0) { shs[wid] = s; shs2[wid] = s2; shmn[wid] = mn; shmx[wid] = mx; }
    __syncthreads();
    if (tid == 0) {
        double S  = shs[0] + shs[1] + shs[2] + shs[3];
        double S2 = shs2[0] + shs2[1] + shs2[2] + shs2[3];
        float MN = fminf(fminf(shmn[0], shmn[1]), fminf(shmn[2], shmn[3]));
        float MX = fmaxf(fmaxf(shmx[0], shmx[1]), fmaxf(shmx[2], shmx[3]));
        const double n = (double)NPIXTOT;
        double var = (S2 - S * S / n) / (n - 1.0);
        double sd = sqrt(var > 0.0 ? var : 0.0);
        double range = (double)MX - (double)MN;
        double ct = sd / range;             /* std of doubly-normalized x */
        int flag = (ct < 0.05) ? 1 : 0;
        double beta = 10.0 * ct;
        double cl = 1.0 / (1.0 - beta) + beta;
        double mv = floor(cl * (double)TPIX / (double)NBINS);
        if (mv < 1.0) mv = 1.0;
        params[0] = MN;
        params[1] = (float)(1.0 / range);
        params[2] = (float)mv;
        ((int*)params)[3] = flag;
    }
}

/* ---------------- kernel 3: per-tile histogram (one block per tile) ------ */
/* Input distribution is extremely peaked (normal^3 min-max normalized), so */
/* most lanes of a wave hit the SAME bin -> same-address LDS atomicAdd      */
/* serializes ~64-way. Fix: 3 rounds of match-any ballot aggregation (one   */
/* atomic per bin-class per wave, leader adds popcount), then a low-        */
/* conflict direct-atomic fallback for straggler lanes.                     */
__global__ __launch_bounds__(256) void k_hist(const float* __restrict__ x,
                                              const float* __restrict__ params,
                                              unsigned* __restrict__ hist) {
    __shared__ unsigned lh[NBINS];
    int tid = threadIdx.x;
    int t = blockIdx.x;
    int lane = tid & 63;
    lh[tid] = 0;
    __syncthreads();
    float xmin = params[0], inv = params[1];
    int c = t >> 6, gy = (t >> 3) & 7, gx = t & 7;
    const float* base = x + ((long)c * NH + (long)gy * NTH) * NW + gx * NTW;
    #pragma unroll
    for (int j = 0; j < 16; j++) {
        int l = j * 256 + tid;            /* float4 id within tile: 4096 total */
        int th = l >> 5, tw4 = l & 31;
        float4 v = *(const float4*)(base + (long)th * NW + tw4 * 4);
        float zv[4] = {v.x, v.y, v.z, v.w};
        #pragma unroll
        for (int k = 0; k < 4; k++) {
            float z = (zv[k] - xmin) * inv;
            int b = (int)(z * 256.0f);
            b = b < 0 ? 0 : (b > 255 ? 255 : b);
            unsigned long long alive = __ballot(1);   /* all 64 lanes */
            #pragma unroll
            for (int r = 0; r < 3; r++) {
                if (!alive) break;                    /* uniform */
                int leader = (int)(__ffsll((long long)alive) - 1);
                int lb = __shfl(b, leader);
                unsigned long long m = __ballot(b == lb) & alive;
                if (lane == leader) atomicAdd(&lh[lb], (unsigned)__popcll(m));
                alive &= ~m;
            }
            if ((alive >> lane) & 1ull) atomicAdd(&lh[b], 1u);
        }
    }
    __syncthreads();
    hist[t * NBINS + tid] = lh[tid];
}

/* ---------------- kernel 4: clip+redistribute+cdf -> LUT ----------------- */
__global__ __launch_bounds__(256) void k_lut(const unsigned* __restrict__ hist,
                                             const float* __restrict__ params,
                                             float* __restrict__ lut) {
    int tid = threadIdx.x;
    int t = blockIdx.x;
    int mv = (int)params[2];
    int h = (int)hist[t * NBINS + tid];
    int cl = h < mv ? h : mv;
    __shared__ int sh[NBINS];
    sh[tid] = cl;
    __syncthreads();
    /* Hillis-Steele inclusive scan of clipped counts */
    for (int o = 1; o < NBINS; o <<= 1) {
        int v = (tid >= o) ? sh[tid - o] : 0;
        __syncthreads();
        sh[tid] += v;
        __syncthreads();
    }
    int total = sh[NBINS - 1];
    int cdfc = sh[tid];
    int excess = TPIX - total;
    int residual = excess & (NBINS - 1);
    int redist = excess >> 8;
    /* cdf of (clipped + redist + (bin<residual)) */
    int cdf = cdfc + redist * (tid + 1) + ((tid + 1) < residual ? (tid + 1) : residual);
    float lv = floorf(fminf((float)cdf * 255.0f / 16384.0f, 255.0f));
    lut[t * NBINS + tid] = lv < 0.0f ? 0.0f : lv;
}

/* ---------------- kernel 5: bilinear LUT interp + log2(1+x) -------------- */
__global__ __launch_bounds__(256) void k_out(const float* __restrict__ x,
                                             const float* __restrict__ params,
                                             const float* __restrict__ lut,
                                             float* __restrict__ out) {
    int tid = threadIdx.x;
    long fid = (long)blockIdx.x * 256 + tid;   /* float4 index */
    long p = fid * 4;
    int w = (int)(p & (NW - 1));
    int h = (int)((p >> 10) & (NH - 1));
    int c = (int)(p >> 20);
    float xmin = params[0], inv = params[1];
    int flag = ((const int*)params)[3];
    float4 v = *(const float4*)(x + p);
    float gy = (h + 0.5f) * (1.0f / NTH) - 0.5f;
    float fy = floorf(gy);
    float wy = gy - fy;
    int y0 = (int)fy; y0 = y0 < 0 ? 0 : (y0 > 7 ? 7 : y0);
    int y1 = y0 + 1 > 7 ? 7 : y0 + 1;
    const float* lutc = lut + (long)c * 64 * NBINS;
    float zv[4] = {v.x, v.y, v.z, v.w};
    float o4[4];
    #pragma unroll
    for (int k = 0; k < 4; k++) {
        float z = (zv[k] - xmin) * inv;
        float val;
        if (flag) {
            int wk = w + k;
            float gx = (wk + 0.5f) * (1.0f / NTW) - 0.5f;
            float fx = floorf(gx);
            float wx = gx - fx;
            int x0 = (int)fx; x0 = x0 < 0 ? 0 : (x0 > 7 ? 7 : x0);
            int x1 = x0 + 1 > 7 ? 7 : x0 + 1;
            int b = (int)(z * 255.0f);
            b = b < 0 ? 0 : (b > 255 ? 255 : b);
            const float* l00 = lutc + (y0 * 8 + x0) * NBINS;
            const float* l01 = lutc + (y0 * 8 + x1) * NBINS;
            const float* l10 = lutc + (y1 * 8 + x0) * NBINS;
            const float* l11 = lutc + (y1 * 8 + x1) * NBINS;
            float top = l00[b] * (1.0f - wx) + l01[b] * wx;
            float bot = l10[b] * (1.0f - wx) + l11[b] * wx;
            val = (top * (1.0f - wy) + bot * wy) * (1.0f / 255.0f);
        } else {
            val = z;
        }
        o4[k] = log2f(1.0f + val);
    }
    *(float4*)(out + p) = make_float4(o4[0], o4[1], o4[2], o4[3]);
}

extern "C" void kernel_launch(void* const* d_in, const int* in_sizes, int n_in,
                              void* d_out, int out_size, void* d_ws, size_t ws_size,
                              hipStream_t stream) {
    const float* x = (const float*)d_in[0];
    float* out = (float*)d_out;
    char* ws = (char*)d_ws;
    double* ps   = (double*)(ws + OFF_PSUM);
    double* ps2  = (double*)(ws + OFF_PSQ);
    float* pmn   = (float*)(ws + OFF_PMIN);
    float* pmx   = (float*)(ws + OFF_PMAX);
    float* params= (float*)(ws + OFF_PARAMS);
    unsigned* hist = (unsigned*)(ws + OFF_HIST);
    float* lut   = (float*)(ws + OFF_LUT);

    k_reduce<<<2048, 256, 0, stream>>>(x, ps, ps2, pmn, pmx);
    k_params<<<1, 256, 0, stream>>>(ps, ps2, pmn, pmx, params);
    k_hist<<<NTILES, 256, 0, stream>>>(x, params, hist);
    k_lut<<<NTILES, 256, 0, stream>>>(hist, params, lut);
    k_out<<<NPIXTOT / 1024, 256, 0, stream>>>(x, params, lut, out);
}

// Round 4
// 297.850 us; speedup vs baseline: 1.1482x; 1.0917x over previous
//
#include <hip/hip_runtime.h>
#include <math.h>

#define NC 32
#define NH 1024
#define NW 1024
#define NTH 128
#define NTW 128
#define NBINS 256
#define NTILES (NC*8*8)              /* 2048 */
#define NPIXTOT (NC*NH*NW)           /* 33554432 */
#define TPIX (NTH*NTW)               /* 16384 */

/* workspace layout (bytes) */
#define OFF_PSUM   0                          /* double[2048] */
#define OFF_PSQ    16384                      /* double[2048] */
#define OFF_PMIN   32768                      /* float[2048]  */
#define OFF_PMAX   40960                      /* float[2048]  */
#define OFF_PARAMS 49152                      /* float[16]    */
#define OFF_LUT8   65536                      /* u8[NTILES*NBINS] = 512KB */

/* ---------------- kernel 1: fused sum/sumsq/min/max partial reduce ------- */
__global__ __launch_bounds__(256) void k_reduce(const float* __restrict__ x,
                                                double* __restrict__ ps,
                                                double* __restrict__ ps2,
                                                float* __restrict__ pmn,
                                                float* __restrict__ pmx) {
    int tid = threadIdx.x;
    long g = (long)blockIdx.x * 256 + tid;
    double s = 0.0, s2 = 0.0;
    float mn = INFINITY, mx = -INFINITY;
    const float4* x4 = (const float4*)x;
    const long n4 = NPIXTOT / 4;
    for (long i = g; i < n4; i += (long)2048 * 256) {
        float4 v = x4[i];
        float sf  = (v.x + v.y) + (v.z + v.w);
        float s2f = fmaf(v.x, v.x, fmaf(v.y, v.y, fmaf(v.z, v.z, v.w * v.w)));
        s  += (double)sf;
        s2 += (double)s2f;
        mn = fminf(mn, fminf(fminf(v.x, v.y), fminf(v.z, v.w)));
        mx = fmaxf(mx, fmaxf(fmaxf(v.x, v.y), fmaxf(v.z, v.w)));
    }
    for (int o = 32; o; o >>= 1) {
        s  += __shfl_down(s, o);
        s2 += __shfl_down(s2, o);
        mn = fminf(mn, __shfl_down(mn, o));
        mx = fmaxf(mx, __shfl_down(mx, o));
    }
    __shared__ double shs[4], shs2[4];
    __shared__ float shmn[4], shmx[4];
    int wid = tid >> 6, lane = tid & 63;
    if (lane == 0) { shs[wid] = s; shs2[wid] = s2; shmn[wid] = mn; shmx[wid] = mx; }
    __syncthreads();
    if (tid == 0) {
        double S  = shs[0] + shs[1] + shs[2] + shs[3];
        double S2 = shs2[0] + shs2[1] + shs2[2] + shs2[3];
        float MN = fminf(fminf(shmn[0], shmn[1]), fminf(shmn[2], shmn[3]));
        float MX = fmaxf(fmaxf(shmx[0], shmx[1]), fmaxf(shmx[2], shmx[3]));
        ps[blockIdx.x] = S; ps2[blockIdx.x] = S2; pmn[blockIdx.x] = MN; pmx[blockIdx.x] = MX;
    }
}

/* ---------------- kernel 2: final reduce + scalar params ----------------- */
__global__ __launch_bounds__(256) void k_params(const double* __restrict__ ps,
                                                const double* __restrict__ ps2,
                                                const float* __restrict__ pmn,
                                                const float* __restrict__ pmx,
                                                float* __restrict__ params) {
    int tid = threadIdx.x;
    double s = 0.0, s2 = 0.0;
    float mn = INFINITY, mx = -INFINITY;
    for (int i = tid; i < 2048; i += 256) {
        s += ps[i]; s2 += ps2[i];
        mn = fminf(mn, pmn[i]); mx = fmaxf(mx, pmx[i]);
    }
    for (int o = 32; o; o >>= 1) {
        s  += __shfl_down(s, o);
        s2 += __shfl_down(s2, o);
        mn = fminf(mn, __shfl_down(mn, o));
        mx = fmaxf(mx, __shfl_down(mx, o));
    }
    __shared__ double shs[4], shs2[4];
    __shared__ float shmn[4], shmx[4];
    int wid = tid >> 6, lane = tid & 63;
    if (lane == 0) { shs[wid] = s; shs2[wid] = s2; shmn[wid] = mn; shmx[wid] = mx; }
    __syncthreads();
    if (tid == 0) {
        double S  = shs[0] + shs[1] + shs[2] + shs[3];
        double S2 = shs2[0] + shs2[1] + shs2[2] + shs2[3];
        float MN = fminf(fminf(shmn[0], shmn[1]), fminf(shmn[2], shmn[3]));
        float MX = fmaxf(fmaxf(shmx[0], shmx[1]), fmaxf(shmx[2], shmx[3]));
        const double n = (double)NPIXTOT;
        double var = (S2 - S * S / n) / (n - 1.0);
        double sd = sqrt(var > 0.0 ? var : 0.0);
        double range = (double)MX - (double)MN;
        double ct = sd / range;
        int flag = (ct < 0.05) ? 1 : 0;
        double beta = 10.0 * ct;
        double cl = 1.0 / (1.0 - beta) + beta;
        double mv = floor(cl * (double)TPIX / (double)NBINS);
        if (mv < 1.0) mv = 1.0;
        params[0] = MN;
        params[1] = (float)(1.0 / range);
        params[2] = (float)mv;
        ((int*)params)[3] = flag;
    }
}

/* ------- kernel 3: per-tile histogram + clip/redistribute/scan -> u8 LUT -- */
/* Per-wave private histograms kill cross-wave LDS-atomic serialization;    */
/* ballot-3 aggregation kills most within-wave same-address serialization.  */
__global__ __launch_bounds__(256) void k_histlut(const float* __restrict__ x,
                                                 const float* __restrict__ params,
                                                 unsigned char* __restrict__ lut8) {
    __shared__ unsigned lh[4 * NBINS];   /* 4 per-wave private histograms */
    __shared__ int sh[NBINS];
    int tid = threadIdx.x;
    int t = blockIdx.x;
    int lane = tid & 63;
    int wid = tid >> 6;
    #pragma unroll
    for (int w = 0; w < 4; w++) lh[w * NBINS + tid] = 0;
    __syncthreads();
    float xmin = params[0], inv = params[1];
    int c = t >> 6, gy = (t >> 3) & 7, gx = t & 7;
    const float* base = x + ((long)c * NH + (long)gy * NTH) * NW + gx * NTW;
    unsigned* mylh = lh + wid * NBINS;
    #pragma unroll 4
    for (int j = 0; j < 16; j++) {
        int l = j * 256 + tid;            /* float4 id within tile: 4096 total */
        int th = l >> 5, tw4 = l & 31;
        float4 v = *(const float4*)(base + (long)th * NW + tw4 * 4);
        float zv[4] = {v.x, v.y, v.z, v.w};
        #pragma unroll
        for (int k = 0; k < 4; k++) {
            float z = (zv[k] - xmin) * inv;
            int b = (int)(z * 256.0f);
            b = b < 0 ? 0 : (b > 255 ? 255 : b);
            unsigned long long alive = __ballot(1);
            #pragma unroll
            for (int r = 0; r < 3; r++) {
                if (!alive) break;
                int leader = (int)(__ffsll((long long)alive) - 1);
                int lb = __shfl(b, leader);
                unsigned long long m = __ballot(b == lb) & alive;
                if (lane == leader) atomicAdd(&mylh[lb], (unsigned)__popcll(m));
                alive &= ~m;
            }
            if ((alive >> lane) & 1ull) atomicAdd(&mylh[b], 1u);
        }
    }
    __syncthreads();
    /* merge 4 wave hists, clip, scan, emit u8 LUT */
    int mv = (int)params[2];
    int h = (int)(lh[tid] + lh[NBINS + tid] + lh[2 * NBINS + tid] + lh[3 * NBINS + tid]);
    int cl = h < mv ? h : mv;
    sh[tid] = cl;
    __syncthreads();
    for (int o = 1; o < NBINS; o <<= 1) {
        int v = (tid >= o) ? sh[tid - o] : 0;
        __syncthreads();
        sh[tid] += v;
        __syncthreads();
    }
    int total = sh[NBINS - 1];
    int cdfc = sh[tid];
    int excess = TPIX - total;
    int residual = excess & (NBINS - 1);
    int redist = excess >> 8;
    int cdf = cdfc + redist * (tid + 1) + ((tid + 1) < residual ? (tid + 1) : residual);
    float lv = floorf(fminf((float)cdf * 255.0f / 16384.0f, 255.0f));
    int iv = (int)(lv < 0.0f ? 0.0f : lv);
    lut8[t * NBINS + tid] = (unsigned char)iv;
}

/* ---------------- kernel 4: bilinear LUT interp + log2(1+x) -------------- */
/* One block per image row: stage the 16 relevant LUTs (2 tile-rows x 8     */
/* cols, u8) into 4KB LDS; gathers become LDS byte reads where same-address */
/* (peaked bins) broadcasts for free.                                       */
__global__ __launch_bounds__(256) void k_out(const float* __restrict__ x,
                                             const float* __restrict__ params,
                                             const unsigned char* __restrict__ lut8,
                                             float* __restrict__ out) {
    __shared__ unsigned char slut[4096];  /* [2 tile-rows][8 cols][256 bins] */
    int tid = threadIdx.x;
    int r = blockIdx.x;                   /* image row id: c*1024 + h */
    int c = r >> 10;
    int h = r & (NH - 1);
    float xmin = params[0], inv = params[1];
    int flag = ((const int*)params)[3];
    /* uniform per-row y coords */
    float gy = (h + 0.5f) * (1.0f / NTH) - 0.5f;
    float fy = floorf(gy);
    float wy = gy - fy;
    int y0 = (int)fy; y0 = y0 < 0 ? 0 : (y0 > 7 ? 7 : y0);
    int y1 = y0 + 1 > 7 ? 7 : y0 + 1;
    /* stage two 2KB LUT rows */
    const unsigned char* src0 = lut8 + ((long)c * 64 + y0 * 8) * NBINS;
    const unsigned char* src1 = lut8 + ((long)c * 64 + y1 * 8) * NBINS;
    if (tid < 128) {
        *(uint4*)(slut + tid * 16) = *(const uint4*)(src0 + tid * 16);
    } else {
        int u = tid - 128;
        *(uint4*)(slut + 2048 + u * 16) = *(const uint4*)(src1 + u * 16);
    }
    __syncthreads();
    long p = ((long)r << 10) + tid * 4;
    float4 v = *(const float4*)(x + p);
    float zv[4] = {v.x, v.y, v.z, v.w};
    float o4[4];
    #pragma unroll
    for (int k = 0; k < 4; k++) {
        float z = (zv[k] - xmin) * inv;
        float val;
        if (flag) {
            int wk = tid * 4 + k;
            float gxc = (wk + 0.5f) * (1.0f / NTW) - 0.5f;
            float fx = floorf(gxc);
            float wx = gxc - fx;
            int x0 = (int)fx; x0 = x0 < 0 ? 0 : (x0 > 7 ? 7 : x0);
            int x1 = x0 + 1 > 7 ? 7 : x0 + 1;
            int b = (int)(z * 255.0f);
            b = b < 0 ? 0 : (b > 255 ? 255 : b);
            float l00 = (float)slut[x0 * NBINS + b];
            float l01 = (float)slut[x1 * NBINS + b];
            float l10 = (float)slut[2048 + x0 * NBINS + b];
            float l11 = (float)slut[2048 + x1 * NBINS + b];
            float top = l00 * (1.0f - wx) + l01 * wx;
            float bot = l10 * (1.0f - wx) + l11 * wx;
            val = (top * (1.0f - wy) + bot * wy) * (1.0f / 255.0f);
        } else {
            val = z;
        }
        o4[k] = log2f(1.0f + val);
    }
    *(float4*)(out + p) = make_float4(o4[0], o4[1], o4[2], o4[3]);
}

extern "C" void kernel_launch(void* const* d_in, const int* in_sizes, int n_in,
                              void* d_out, int out_size, void* d_ws, size_t ws_size,
                              hipStream_t stream) {
    const float* x = (const float*)d_in[0];
    float* out = (float*)d_out;
    char* ws = (char*)d_ws;
    double* ps   = (double*)(ws + OFF_PSUM);
    double* ps2  = (double*)(ws + OFF_PSQ);
    float* pmn   = (float*)(ws + OFF_PMIN);
    float* pmx   = (float*)(ws + OFF_PMAX);
    float* params= (float*)(ws + OFF_PARAMS);
    unsigned char* lut8 = (unsigned char*)(ws + OFF_LUT8);

    k_reduce<<<2048, 256, 0, stream>>>(x, ps, ps2, pmn, pmx);
    k_params<<<1, 256, 0, stream>>>(ps, ps2, pmn, pmx, params);
    k_histlut<<<NTILES, 256, 0, stream>>>(x, params, lut8);
    k_out<<<NC * NH, 256, 0, stream>>>(x, params, lut8, out);
}